// Round 3
// baseline (308.324 us; speedup 1.0000x reference)
//
#include <hip/hip_runtime.h>

// Problem constants: VOCAB=100000, EMB=300, B=2048, L=200, H=128, OUT=20
#define VOCAB 100000
#define BB   2048
#define LL   200
#define EMB  300
#define HH   128
#define OUTD 20
#define NSRT 256        // bitonic sort width (LL padded with INT_MAX)
#define RPW  (LL / 4)   // 50 rows per wave

// =====================================================================
// Kernel 1: P = table @ W1   (fp32 tiled GEMM, 100000x300 @ 300x128)
// v3: register double-buffering (T14 async-split). Next K-step's A+B
// global loads are issued into 32 VGPRs BEFORE the 32-k FMA phase; the
// ~4096-cyc compute covers the ~500-900 cyc HBM/L2 latency that v2
// exposed at every barrier (VALUBusy was 42%). launch_bounds(256,3):
// unified-file budget is ~124/wave already (60 VGPR + 64 acc); +32
// staging regs needs the 170-reg cap, still 3 waves/SIMD = status quo.
// =====================================================================
#define BMp 128
#define BKp 32
#define KSTEPS 10   // ceil(300/32); staging zero-fills k>=300
#define BSW 144     // swizzled B row stride

__global__ __launch_bounds__(256, 3) void proj_gemm(
    const float* __restrict__ table,   // [VOCAB, EMB]
    const float* __restrict__ W1,      // [EMB, HH]
    float*       __restrict__ P)       // [VOCAB, HH]
{
    __shared__ float A_s[BKp][BMp + 4];   // [k][row] transposed
    __shared__ float B_s[BKp][BSW];       // [k][swizzled col]

    const int t    = threadIdx.x;
    const int tx   = t & 15;              // output col group (8 cols)
    const int ty   = t >> 4;              // output row group (8 rows)
    const int row0 = blockIdx.x * BMp;

    // swizzled read base: float4 chunk q=2*tx -> q' = q + (q>>3)
    const int bswz = 8 * tx + 4 * (tx >> 2);

    // staging geometry (same coverage as v2)
    const int ar      = t >> 1;               // A row within tile
    const int kc      = (t & 1) * 16;         // A k-chunk base
    const int arow    = row0 + ar;
    const bool arow_ok = (arow < VOCAB);
    const float* Abase = table + (size_t)arow * EMB;
    const int brk     = t >> 3;               // B k-row within tile
    const int bm      = t & 7;                // B col chunk group

    float4 ra[4], rb[4];                      // staging regs (32 VGPR)

    float acc[8][8];
    #pragma unroll
    for (int i = 0; i < 8; ++i)
        #pragma unroll
        for (int j = 0; j < 8; ++j) acc[i][j] = 0.f;

    // ---- prologue: stage K-step 0
    {
        #pragma unroll
        for (int i = 0; i < 4; ++i) {
            const int k = kc + 4 * i;
            ra[i] = (arow_ok && k < EMB) ? *(const float4*)(Abase + k)
                                         : make_float4(0.f, 0.f, 0.f, 0.f);
        }
        #pragma unroll
        for (int i = 0; i < 4; ++i)
            rb[i] = *(const float4*)(W1 + (size_t)brk * HH + bm * 16 + 4 * i);
        #pragma unroll
        for (int i = 0; i < 4; ++i) {
            const int kk = kc + 4 * i;
            A_s[kk + 0][ar] = ra[i].x; A_s[kk + 1][ar] = ra[i].y;
            A_s[kk + 2][ar] = ra[i].z; A_s[kk + 3][ar] = ra[i].w;
        }
        #pragma unroll
        for (int i = 0; i < 4; ++i) {
            const int q = bm * 4 + i;
            *(float4*)&B_s[brk][4 * q + 4 * (q >> 3)] = rb[i];
        }
    }
    __syncthreads();

    for (int ks = 0; ks < KSTEPS; ++ks) {
        // ---- issue next K-step's global loads (latency hides under FMA)
        if (ks + 1 < KSTEPS) {
            const int kbase = (ks + 1) * BKp;
            #pragma unroll
            for (int i = 0; i < 4; ++i) {
                const int k = kbase + kc + 4 * i;
                ra[i] = (arow_ok && k < EMB) ? *(const float4*)(Abase + k)
                                             : make_float4(0.f, 0.f, 0.f, 0.f);
            }
            const int kb = kbase + brk;
            #pragma unroll
            for (int i = 0; i < 4; ++i)
                rb[i] = (kb < EMB) ? *(const float4*)(W1 + (size_t)kb * HH + bm * 16 + 4 * i)
                                   : make_float4(0.f, 0.f, 0.f, 0.f);
        }

        // ---- 8x8 micro-tile over current LDS buffer
        #pragma unroll 4
        for (int k = 0; k < BKp; ++k) {
            const float4 a0  = *(const float4*)&A_s[k][ty * 8];
            const float4 a1  = *(const float4*)&A_s[k][ty * 8 + 4];
            const float4 b0  = *(const float4*)&B_s[k][bswz];
            const float4 b1v = *(const float4*)&B_s[k][bswz + 4];
            const float a[8]  = {a0.x, a0.y, a0.z, a0.w, a1.x, a1.y, a1.z, a1.w};
            const float bb[8] = {b0.x, b0.y, b0.z, b0.w, b1v.x, b1v.y, b1v.z, b1v.w};
            #pragma unroll
            for (int i = 0; i < 8; ++i)
                #pragma unroll
                for (int j = 0; j < 8; ++j)
                    acc[i][j] = fmaf(a[i], bb[j], acc[i][j]);
        }
        __syncthreads();          // all reads of the buffer done

        if (ks + 1 < KSTEPS) {
            #pragma unroll
            for (int i = 0; i < 4; ++i) {
                const int kk = kc + 4 * i;
                A_s[kk + 0][ar] = ra[i].x; A_s[kk + 1][ar] = ra[i].y;
                A_s[kk + 2][ar] = ra[i].z; A_s[kk + 3][ar] = ra[i].w;
            }
            #pragma unroll
            for (int i = 0; i < 4; ++i) {
                const int q = bm * 4 + i;
                *(float4*)&B_s[brk][4 * q + 4 * (q >> 3)] = rb[i];
            }
            __syncthreads();      // writes visible before next compute
        }
    }

    #pragma unroll
    for (int i = 0; i < 8; ++i) {
        const int row = row0 + ty * 8 + i;
        if (row < VOCAB) {
            const float4 o0 = make_float4(acc[i][0], acc[i][1], acc[i][2], acc[i][3]);
            const float4 o1 = make_float4(acc[i][4], acc[i][5], acc[i][6], acc[i][7]);
            *(float4*)(P + (size_t)row * HH + tx * 8)     = o0;
            *(float4*)(P + (size_t)row * HH + tx * 8 + 4) = o1;
        }
    }
}

// =====================================================================
// Kernel 2: gather-sum over P (512 B rows) + tiny MLP epilogue.
// v3: per-block PHASE ROTATION of the sorted sweep. The sorted ascending
// sweep synchronized all 2048 blocks onto the same ~2-4 MB vocab band at
// every instant (order statistics of 200 uniform draws) -> chip-wide
// L3/L2 channel hotspot, measured 1.34 TB/s effective. Rotating each
// block's start position by (b*29)%50 keeps per-block ascending locality
// but decorrelates the bands across blocks.
// =====================================================================
__global__ __launch_bounds__(256) void gather_mlp(
    const int*   __restrict__ x,        // [B, L]
    const int*   __restrict__ lengths,  // [B]
    const float* __restrict__ P,        // [VOCAB, HH]
    const float* __restrict__ b1,       // [HH]
    const float* __restrict__ W2,       // [HH, OUT]
    const float* __restrict__ b2,       // [OUT]
    float*       __restrict__ out)      // [B, OUT]
{
    __shared__ int   idx_s[NSRT];
    __shared__ float part_f[4][256];    // [wave][half*128 + col]
    __shared__ float h_s[HH];

    const int b    = blockIdx.x;
    const int t    = threadIdx.x;
    const int w    = t >> 6;
    const int lane = t & 63;

    idx_s[t] = (t < LL) ? x[b * LL + t] : 0x7FFFFFFF;
    __syncthreads();

    // ---- bitonic sort ascending over 256 slots
    #pragma unroll
    for (int k = 2; k <= NSRT; k <<= 1) {
        #pragma unroll
        for (int j = k >> 1; j > 0; j >>= 1) {
            const int ixj = t ^ j;
            if (ixj > t) {
                const int a0 = idx_s[t];
                const int a1 = idx_s[ixj];
                const bool up = ((t & k) == 0);
                if ((a0 > a1) == up) { idx_s[t] = a1; idx_s[ixj] = a0; }
            }
            __syncthreads();
        }
    }

    // per-block phase: rotate start position within the sorted order
    const int ph = (b * 29) % RPW;
    int jrot = lane + ph;
    if (jrot >= RPW) jrot -= RPW;       // (lane+ph) mod 50, lane<50, ph<50
    const int myidx = (lane < RPW) ? idx_s[w + 4 * jrot] : 0;

    // ---- gather-sum: two rows per full-wave dwordx4 load
    float4 acc = make_float4(0.f, 0.f, 0.f, 0.f);
    #pragma unroll 5
    for (int i = 0; i < RPW / 2; ++i) {                       // 25 iterations
        const int r0 = __builtin_amdgcn_readlane(myidx, 2 * i);
        const int r1 = __builtin_amdgcn_readlane(myidx, 2 * i + 1);
        const int ridx = (lane < 32) ? r0 : r1;
        const float4 v = ((const float4*)(P + (size_t)ridx * HH))[lane & 31];
        acc.x += v.x; acc.y += v.y; acc.z += v.z; acc.w += v.w;
    }
    // lane l holds partial of cols (l&31)*4..+3, half = l>>5
    *(float4*)&part_f[w][lane << 2] = acc;
    __syncthreads();

    // ---- reduce 8 partials per col, scale, +b1, relu
    const float inv_len = 1.0f / (float)lengths[b];
    if (t < HH) {
        float s = 0.f;
        #pragma unroll
        for (int ww = 0; ww < 4; ++ww)
            s += part_f[ww][t] + part_f[ww][128 + t];
        h_s[t] = fmaxf(fmaf(s, inv_len, b1[t]), 0.f);
    }
    __syncthreads();

    // ---- logits = h @ W2 + b2
    if (t < OUTD) {
        float o = b2[t];
        #pragma unroll
        for (int k = 0; k < HH; ++k)
            o = fmaf(h_s[k], W2[k * OUTD + t], o);
        out[b * OUTD + t] = o;
    }
}

// =====================================================================
// Fallback: prior session's proven fused kernel — used only if the
// workspace is too small for P.
// =====================================================================
__global__ __launch_bounds__(256) void fused_dnn(
    const int*   __restrict__ x,
    const int*   __restrict__ lengths,
    const float* __restrict__ table,
    const float* __restrict__ W1,
    const float* __restrict__ b1,
    const float* __restrict__ W2,
    const float* __restrict__ b2,
    float*       __restrict__ out)
{
    __shared__ int    idx_s[NSRT];
    __shared__ float4 part_s[4][76];
    __shared__ float  rep_s[EMB];
    __shared__ float  h_part[2][HH];
    __shared__ float  h_s[HH];

    const int b    = blockIdx.x;
    const int t    = threadIdx.x;
    const int w    = t >> 6;
    const int lane = t & 63;

    idx_s[t] = (t < LL) ? x[b * LL + t] : 0x7FFFFFFF;
    __syncthreads();

    #pragma unroll
    for (int k = 2; k <= NSRT; k <<= 1) {
        #pragma unroll
        for (int j = k >> 1; j > 0; j >>= 1) {
            const int ixj = t ^ j;
            if (ixj > t) {
                const int a0 = idx_s[t];
                const int a1 = idx_s[ixj];
                const bool up = ((t & k) == 0);
                if ((a0 > a1) == up) { idx_s[t] = a1; idx_s[ixj] = a0; }
            }
            __syncthreads();
        }
    }

    const int myidx = (lane < RPW) ? idx_s[w + 4 * lane] : 0;

    float4 acc_a = make_float4(0.f, 0.f, 0.f, 0.f);
    float4 acc_b = make_float4(0.f, 0.f, 0.f, 0.f);
    const bool hasb = (lane < (EMB / 4 - 64));

    #pragma unroll 5
    for (int i = 0; i < RPW; ++i) {
        const int ridx = __builtin_amdgcn_readlane(myidx, i);
        const float4* row = (const float4*)(table + (size_t)ridx * EMB);
        float4 va = row[lane];
        acc_a.x += va.x; acc_a.y += va.y; acc_a.z += va.z; acc_a.w += va.w;
        if (hasb) {
            float4 vb = row[64 + lane];
            acc_b.x += vb.x; acc_b.y += vb.y; acc_b.z += vb.z; acc_b.w += vb.w;
        }
    }

    part_s[w][lane] = acc_a;
    if (hasb) part_s[w][64 + lane] = acc_b;
    __syncthreads();

    const float inv_len = 1.0f / (float)lengths[b];
    const float* ps = (const float*)part_s;
    {
        float s = ps[t] + ps[304 + t] + ps[608 + t] + ps[912 + t];
        rep_s[t] = s * inv_len;
    }
    if (t < (EMB - 256)) {
        int c = 256 + t;
        float s = ps[c] + ps[304 + c] + ps[608 + c] + ps[912 + c];
        rep_s[c] = s * inv_len;
    }
    __syncthreads();

    {
        const int half = t >> 7;
        const int col  = t & 127;
        float hacc = (half == 0) ? b1[col] : 0.0f;
        const int k0 = half * (EMB / 2);
        #pragma unroll 5
        for (int k = k0; k < k0 + EMB / 2; ++k)
            hacc = fmaf(rep_s[k], W1[k * HH + col], hacc);
        h_part[half][col] = hacc;
    }
    __syncthreads();
    if (t < HH)
        h_s[t] = fmaxf(h_part[0][t] + h_part[1][t], 0.0f);
    __syncthreads();

    if (t < OUTD) {
        float oacc = b2[t];
        #pragma unroll
        for (int k = 0; k < HH; ++k)
            oacc = fmaf(h_s[k], W2[k * OUTD + t], oacc);
        out[b * OUTD + t] = oacc;
    }
}

extern "C" void kernel_launch(void* const* d_in, const int* in_sizes, int n_in,
                              void* d_out, int out_size, void* d_ws, size_t ws_size,
                              hipStream_t stream) {
    const int*   x       = (const int*)  d_in[0];
    const int*   lengths = (const int*)  d_in[1];
    const float* table   = (const float*)d_in[2];
    const float* W1      = (const float*)d_in[3];
    const float* b1      = (const float*)d_in[4];
    const float* W2      = (const float*)d_in[5];
    const float* b2      = (const float*)d_in[6];
    float*       out     = (float*)d_out;

    const size_t PBYTES = (size_t)VOCAB * HH * sizeof(float);   // 51.2 MB

    if (d_ws != nullptr && ws_size >= PBYTES) {
        float* P = (float*)d_ws;
        const int mtiles = (VOCAB + BMp - 1) / BMp;             // 782
        proj_gemm<<<mtiles, 256, 0, stream>>>(table, W1, P);
        gather_mlp<<<BB, 256, 0, stream>>>(x, lengths, P, b1, W2, b2, out);
    } else {
        fused_dnn<<<BB, 256, 0, stream>>>(x, lengths, table, W1, b1, W2, b2, out);
    }
}

// Round 4
// 305.146 us; speedup vs baseline: 1.0104x; 1.0104x over previous
//
#include <hip/hip_runtime.h>

typedef _Float16 f16;
typedef _Float16 f16x8 __attribute__((ext_vector_type(8)));

// Problem constants: VOCAB=100000, EMB=300, B=2048, L=200, H=128, OUT=20
#define VOCAB 100000
#define BB   2048
#define LL   200
#define EMB  300
#define HH   128
#define OUTD 20
#define NSRT 256        // bitonic sort width (LL padded with INT_MAX)
#define RPW  50         // sorted rows per wave

// =====================================================================
// Kernel 1: P = table @ W1, P stored FP16 (100000x128).
// v4 = v3 (reg double-buffer) + fp16 epilogue. fp16 chosen over bf16:
// P ~ N(0,1) needs no range, fp16 eps 2^-11 keeps worst-case (len=1)
// logit error ~8e-3 tail vs existing 0.0156 fp32-reassociation absmax.
// Compute stays fp32 VALU (MFMA split-bf16 rewrite is the next lever).
// =====================================================================
#define BMp 128
#define BKp 32
#define KSTEPS 10   // ceil(300/32); staging zero-fills k>=300
#define BSW 144     // swizzled B row stride

__global__ __launch_bounds__(256, 3) void proj_gemm(
    const float* __restrict__ table,   // [VOCAB, EMB]
    const float* __restrict__ W1,      // [EMB, HH]
    f16*         __restrict__ P)       // [VOCAB, HH] fp16
{
    __shared__ float A_s[BKp][BMp + 4];   // [k][row] transposed
    __shared__ float B_s[BKp][BSW];       // [k][swizzled col]

    const int t    = threadIdx.x;
    const int tx   = t & 15;              // output col group (8 cols)
    const int ty   = t >> 4;              // output row group (8 rows)
    const int row0 = blockIdx.x * BMp;

    // swizzled read base: float4 chunk q=2*tx -> q' = q + (q>>3)
    const int bswz = 8 * tx + 4 * (tx >> 2);

    const int ar       = t >> 1;               // A row within tile
    const int kc       = (t & 1) * 16;         // A k-chunk base
    const int arow     = row0 + ar;
    const bool arow_ok = (arow < VOCAB);
    const float* Abase = table + (size_t)arow * EMB;
    const int brk      = t >> 3;               // B k-row within tile
    const int bm       = t & 7;                // B col chunk group

    float4 ra[4], rb[4];                       // staging regs

    float acc[8][8];
    #pragma unroll
    for (int i = 0; i < 8; ++i)
        #pragma unroll
        for (int j = 0; j < 8; ++j) acc[i][j] = 0.f;

    // ---- prologue: stage K-step 0
    {
        #pragma unroll
        for (int i = 0; i < 4; ++i) {
            const int k = kc + 4 * i;
            ra[i] = (arow_ok && k < EMB) ? *(const float4*)(Abase + k)
                                         : make_float4(0.f, 0.f, 0.f, 0.f);
        }
        #pragma unroll
        for (int i = 0; i < 4; ++i)
            rb[i] = *(const float4*)(W1 + (size_t)brk * HH + bm * 16 + 4 * i);
        #pragma unroll
        for (int i = 0; i < 4; ++i) {
            const int kk = kc + 4 * i;
            A_s[kk + 0][ar] = ra[i].x; A_s[kk + 1][ar] = ra[i].y;
            A_s[kk + 2][ar] = ra[i].z; A_s[kk + 3][ar] = ra[i].w;
        }
        #pragma unroll
        for (int i = 0; i < 4; ++i) {
            const int q = bm * 4 + i;
            *(float4*)&B_s[brk][4 * q + 4 * (q >> 3)] = rb[i];
        }
    }
    __syncthreads();

    for (int ks = 0; ks < KSTEPS; ++ks) {
        // ---- issue next K-step's global loads (hide under FMA phase)
        if (ks + 1 < KSTEPS) {
            const int kbase = (ks + 1) * BKp;
            #pragma unroll
            for (int i = 0; i < 4; ++i) {
                const int k = kbase + kc + 4 * i;
                ra[i] = (arow_ok && k < EMB) ? *(const float4*)(Abase + k)
                                             : make_float4(0.f, 0.f, 0.f, 0.f);
            }
            const int kb = kbase + brk;
            #pragma unroll
            for (int i = 0; i < 4; ++i)
                rb[i] = (kb < EMB) ? *(const float4*)(W1 + (size_t)kb * HH + bm * 16 + 4 * i)
                                   : make_float4(0.f, 0.f, 0.f, 0.f);
        }

        // ---- 8x8 micro-tile over current LDS buffer
        #pragma unroll 4
        for (int k = 0; k < BKp; ++k) {
            const float4 a0  = *(const float4*)&A_s[k][ty * 8];
            const float4 a1  = *(const float4*)&A_s[k][ty * 8 + 4];
            const float4 b0  = *(const float4*)&B_s[k][bswz];
            const float4 b1v = *(const float4*)&B_s[k][bswz + 4];
            const float a[8]  = {a0.x, a0.y, a0.z, a0.w, a1.x, a1.y, a1.z, a1.w};
            const float bb[8] = {b0.x, b0.y, b0.z, b0.w, b1v.x, b1v.y, b1v.z, b1v.w};
            #pragma unroll
            for (int i = 0; i < 8; ++i)
                #pragma unroll
                for (int j = 0; j < 8; ++j)
                    acc[i][j] = fmaf(a[i], bb[j], acc[i][j]);
        }
        __syncthreads();

        if (ks + 1 < KSTEPS) {
            #pragma unroll
            for (int i = 0; i < 4; ++i) {
                const int kk = kc + 4 * i;
                A_s[kk + 0][ar] = ra[i].x; A_s[kk + 1][ar] = ra[i].y;
                A_s[kk + 2][ar] = ra[i].z; A_s[kk + 3][ar] = ra[i].w;
            }
            #pragma unroll
            for (int i = 0; i < 4; ++i) {
                const int q = bm * 4 + i;
                *(float4*)&B_s[brk][4 * q + 4 * (q >> 3)] = rb[i];
            }
            __syncthreads();
        }
    }

    // ---- fp16 epilogue: 8 rows x 8 cols per thread, 16 B per row store
    #pragma unroll
    for (int i = 0; i < 8; ++i) {
        const int row = row0 + ty * 8 + i;
        if (row < VOCAB) {
            f16x8 o;
            #pragma unroll
            for (int j = 0; j < 8; ++j) o[j] = (f16)acc[i][j];
            *(f16x8*)(P + (size_t)row * HH + tx * 8) = o;
        }
    }
}

// =====================================================================
// Kernel 2: gather-sum over fp16 P (256 B rows) + tiny MLP epilogue.
// v4: 4 rows per wave-load (lane group g=lane>>4 -> row, c=lane&15 ->
// 16B col chunk). vs v3: bytes 2x down (210->105 MB), lines 2x down,
// wave-loads 2x down (25->13/wave). Every surviving bottleneck
// hypothesis (L3 line service, TLB, per-row cost) scales with at least
// one of these. Wave w owns sorted chunk [50w,50w+50) -> per-load rows
// are 4 consecutive sorted indices. Accumulation fp32.
// =====================================================================
__global__ __launch_bounds__(256) void gather_mlp(
    const int*   __restrict__ x,        // [B, L]
    const int*   __restrict__ lengths,  // [B]
    const f16*   __restrict__ P,        // [VOCAB, HH] fp16
    const float* __restrict__ b1,       // [HH]
    const float* __restrict__ W2,       // [HH, OUT]
    const float* __restrict__ b2,       // [OUT]
    float*       __restrict__ out)      // [B, OUT]
{
    __shared__ int   idx_s[NSRT];
    __shared__ float part_s[16][HH];    // [t>>4][col] 8 KB
    __shared__ float h_s[HH];

    const int b    = blockIdx.x;
    const int t    = threadIdx.x;
    const int w    = t >> 6;
    const int lane = t & 63;

    idx_s[t] = (t < LL) ? x[b * LL + t] : 0x7FFFFFFF;
    __syncthreads();

    // ---- bitonic sort ascending over 256 slots
    #pragma unroll
    for (int k = 2; k <= NSRT; k <<= 1) {
        #pragma unroll
        for (int j = k >> 1; j > 0; j >>= 1) {
            const int ixj = t ^ j;
            if (ixj > t) {
                const int a0 = idx_s[t];
                const int a1 = idx_s[ixj];
                const bool up = ((t & k) == 0);
                if ((a0 > a1) == up) { idx_s[t] = a1; idx_s[ixj] = a0; }
            }
            __syncthreads();
        }
    }

    // wave w owns sorted positions [50w, 50w+50); lane j<50 holds row j
    const int myidx = (lane < RPW) ? idx_s[RPW * w + lane] : 0;

    const int c = lane & 15;            // 16B col chunk (halves 8c..8c+7)
    const size_t coff = (size_t)c * 8;

    float acc[8];
    #pragma unroll
    for (int j = 0; j < 8; ++j) acc[j] = 0.f;

    // ---- 12 iterations x 4 rows
    #pragma unroll
    for (int i = 0; i < 12; ++i) {
        const int r0 = __builtin_amdgcn_readlane(myidx, 4 * i + 0);
        const int r1 = __builtin_amdgcn_readlane(myidx, 4 * i + 1);
        const int r2 = __builtin_amdgcn_readlane(myidx, 4 * i + 2);
        const int r3 = __builtin_amdgcn_readlane(myidx, 4 * i + 3);
        const int rlo  = (lane & 16) ? r1 : r0;
        const int rhi  = (lane & 16) ? r3 : r2;
        const int ridx = (lane & 32) ? rhi : rlo;
        const f16x8 v = *(const f16x8*)(P + (size_t)ridx * HH + coff);
        #pragma unroll
        for (int j = 0; j < 8; ++j) acc[j] += (float)v[j];
    }
    // ---- tail: rows 48,49 on lane groups 0,1 (groups 2,3 masked out)
    {
        const int r0 = __builtin_amdgcn_readlane(myidx, 48);
        const int r1 = __builtin_amdgcn_readlane(myidx, 49);
        const int ridx = (lane & 16) ? r1 : r0;
        const f16x8 v = *(const f16x8*)(P + (size_t)ridx * HH + coff);
        if (lane < 32) {
            #pragma unroll
            for (int j = 0; j < 8; ++j) acc[j] += (float)v[j];
        }
    }

    // partials: 16 groups (t>>4), each covering all 128 cols
    *(float4*)&part_s[t >> 4][c * 8]     = make_float4(acc[0], acc[1], acc[2], acc[3]);
    *(float4*)&part_s[t >> 4][c * 8 + 4] = make_float4(acc[4], acc[5], acc[6], acc[7]);
    __syncthreads();

    // ---- reduce 16 partials per col, scale, +b1, relu
    const float inv_len = 1.0f / (float)lengths[b];
    if (t < HH) {
        float s = 0.f;
        #pragma unroll
        for (int p = 0; p < 16; ++p) s += part_s[p][t];
        h_s[t] = fmaxf(fmaf(s, inv_len, b1[t]), 0.f);
    }
    __syncthreads();

    // ---- logits = h @ W2 + b2
    if (t < OUTD) {
        float o = b2[t];
        #pragma unroll
        for (int k = 0; k < HH; ++k)
            o = fmaf(h_s[k], W2[k * OUTD + t], o);
        out[b * OUTD + t] = o;
    }
}

// =====================================================================
// Fallback: prior session's proven fused kernel — used only if the
// workspace is too small for P.
// =====================================================================
__global__ __launch_bounds__(256) void fused_dnn(
    const int*   __restrict__ x,
    const int*   __restrict__ lengths,
    const float* __restrict__ table,
    const float* __restrict__ W1,
    const float* __restrict__ b1,
    const float* __restrict__ W2,
    const float* __restrict__ b2,
    float*       __restrict__ out)
{
    __shared__ int    idx_s[NSRT];
    __shared__ float4 part_s[4][76];
    __shared__ float  rep_s[EMB];
    __shared__ float  h_part[2][HH];
    __shared__ float  h_s[HH];

    const int b    = blockIdx.x;
    const int t    = threadIdx.x;
    const int w    = t >> 6;
    const int lane = t & 63;

    idx_s[t] = (t < LL) ? x[b * LL + t] : 0x7FFFFFFF;
    __syncthreads();

    #pragma unroll
    for (int k = 2; k <= NSRT; k <<= 1) {
        #pragma unroll
        for (int j = k >> 1; j > 0; j >>= 1) {
            const int ixj = t ^ j;
            if (ixj > t) {
                const int a0 = idx_s[t];
                const int a1 = idx_s[ixj];
                const bool up = ((t & k) == 0);
                if ((a0 > a1) == up) { idx_s[t] = a1; idx_s[ixj] = a0; }
            }
            __syncthreads();
        }
    }

    const int myidx = (lane < RPW) ? idx_s[w + 4 * lane] : 0;

    float4 acc_a = make_float4(0.f, 0.f, 0.f, 0.f);
    float4 acc_b = make_float4(0.f, 0.f, 0.f, 0.f);
    const bool hasb = (lane < (EMB / 4 - 64));

    #pragma unroll 5
    for (int i = 0; i < RPW; ++i) {
        const int ridx = __builtin_amdgcn_readlane(myidx, i);
        const float4* row = (const float4*)(table + (size_t)ridx * EMB);
        float4 va = row[lane];
        acc_a.x += va.x; acc_a.y += va.y; acc_a.z += va.z; acc_a.w += va.w;
        if (hasb) {
            float4 vb = row[64 + lane];
            acc_b.x += vb.x; acc_b.y += vb.y; acc_b.z += vb.z; acc_b.w += vb.w;
        }
    }

    part_s[w][lane] = acc_a;
    if (hasb) part_s[w][64 + lane] = acc_b;
    __syncthreads();

    const float inv_len = 1.0f / (float)lengths[b];
    const float* ps = (const float*)part_s;
    {
        float s = ps[t] + ps[304 + t] + ps[608 + t] + ps[912 + t];
        rep_s[t] = s * inv_len;
    }
    if (t < (EMB - 256)) {
        int c = 256 + t;
        float s = ps[c] + ps[304 + c] + ps[608 + c] + ps[912 + c];
        rep_s[c] = s * inv_len;
    }
    __syncthreads();

    {
        const int half = t >> 7;
        const int col  = t & 127;
        float hacc = (half == 0) ? b1[col] : 0.0f;
        const int k0 = half * (EMB / 2);
        #pragma unroll 5
        for (int k = k0; k < k0 + EMB / 2; ++k)
            hacc = fmaf(rep_s[k], W1[k * HH + col], hacc);
        h_part[half][col] = hacc;
    }
    __syncthreads();
    if (t < HH)
        h_s[t] = fmaxf(h_part[0][t] + h_part[1][t], 0.0f);
    __syncthreads();

    if (t < OUTD) {
        float oacc = b2[t];
        #pragma unroll
        for (int k = 0; k < HH; ++k)
            oacc = fmaf(h_s[k], W2[k * OUTD + t], oacc);
        out[b * OUTD + t] = oacc;
    }
}

extern "C" void kernel_launch(void* const* d_in, const int* in_sizes, int n_in,
                              void* d_out, int out_size, void* d_ws, size_t ws_size,
                              hipStream_t stream) {
    const int*   x       = (const int*)  d_in[0];
    const int*   lengths = (const int*)  d_in[1];
    const float* table   = (const float*)d_in[2];
    const float* W1      = (const float*)d_in[3];
    const float* b1      = (const float*)d_in[4];
    const float* W2      = (const float*)d_in[5];
    const float* b2      = (const float*)d_in[6];
    float*       out     = (float*)d_out;

    const size_t PBYTES = (size_t)VOCAB * HH * sizeof(f16);   // 25.6 MB

    if (d_ws != nullptr && ws_size >= PBYTES) {
        f16* P = (f16*)d_ws;
        const int mtiles = (VOCAB + BMp - 1) / BMp;             // 782
        proj_gemm<<<mtiles, 256, 0, stream>>>(table, W1, P);
        gather_mlp<<<BB, 256, 0, stream>>>(x, lengths, P, b1, W2, b2, out);
    } else {
        fused_dnn<<<BB, 256, 0, stream>>>(x, lengths, table, W1, b1, W2, b2, out);
    }
}

// Round 5
// 247.993 us; speedup vs baseline: 1.2433x; 1.2305x over previous
//
#include <hip/hip_runtime.h>

typedef _Float16 f16;
typedef _Float16 f16x8 __attribute__((ext_vector_type(8)));
typedef float    f32x4 __attribute__((ext_vector_type(4)));

// Problem constants: VOCAB=100000, EMB=300, B=2048, L=200, H=128, OUT=20
#define VOCAB 100000
#define BB   2048
#define LL   200
#define EMB  300
#define HH   128
#define OUTD 20
#define NSRT 256        // bitonic sort width (LL padded with INT_MAX)
#define RPW  50         // sorted rows per wave

#define KPAD 320        // K padded to 10*32 (zeros beyond 300)

// =====================================================================
// Kernel 0: one-time W1 transpose + fp16 hi/lo split, zero-padded K.
// W1t_hi/lo[n][k] (n=0..127, k=0..319) so proj staging loads are
// contiguous 16B chunks. Total 160 KB work — noise.
// =====================================================================
__global__ void w1t_prep(const float* __restrict__ W1,   // [EMB, HH]
                         f16* __restrict__ w1t_hi,       // [HH, KPAD]
                         f16* __restrict__ w1t_lo)       // [HH, KPAD]
{
    const int n = blockIdx.x;          // 0..127
    const int k = threadIdx.x;         // 0..319
    const float v = (k < EMB) ? W1[(size_t)k * HH + n] : 0.f;
    const f16 hi = (f16)v;
    const f16 lo = (f16)(v - (float)hi);
    w1t_hi[(size_t)n * KPAD + k] = hi;
    w1t_lo[(size_t)n * KPAD + k] = lo;
}

// =====================================================================
// Kernel 1: P = table @ W1 via 3-pass split-fp16 MFMA (fp32-accurate).
// v5: the fp32 VALU path was LDS-bound (~73us ds_read floor, VALUBusy
// 46%); MFMA cuts LDS reads/FLOP 8x and moves compute off VALU.
//   tile 128x128x32, 4 waves, wave w owns m-tiles {2w,2w+1} x all 8 n.
//   16x16x32_f16 fragments, fragment-linear LDS (lane l <-> byte l*16,
//   conflict-free b128). A split hi/lo on the fly; B pre-split (w1t).
//   acc += Ah*Bh + Ah*Bl + Al*Bh  (residual Al*Bl ~ 2^-22 — negligible).
// Layouts (m89/m91-verified C/D; A/B per AMD convention):
//   A-frag: lane l -> A[m = l&15][k = 8*(l>>4)+j]
//   B-frag: lane l -> B[k = 8*(l>>4)+j][n = l&15]
//   C/D:    reg j of lane l -> row = 4*(l>>4)+j, col = l&15
// =====================================================================
#define BMp 128
#define BKp 32
#define KSTEPS 10

__global__ __launch_bounds__(256, 3) void proj_mfma(
    const float* __restrict__ table,   // [VOCAB, EMB]
    const f16*   __restrict__ w1t_hi,  // [HH, KPAD]
    const f16*   __restrict__ w1t_lo,  // [HH, KPAD]
    f16*         __restrict__ P)       // [VOCAB, HH] fp16
{
    __shared__ f16 Af_hi[8][64][8];    // [m-tile][lane][8k]  8 KB
    __shared__ f16 Af_lo[8][64][8];
    __shared__ f16 Bf_hi[8][64][8];    // [n-tile][lane][8k]
    __shared__ f16 Bf_lo[8][64][8];

    const int t    = threadIdx.x;
    const int w    = t >> 6;
    const int lane = t & 63;
    const int row0 = blockIdx.x * BMp;

    f32x4 acc[2][8];
    #pragma unroll
    for (int i = 0; i < 2; ++i)
        #pragma unroll
        for (int j = 0; j < 8; ++j) acc[i][j] = (f32x4)0.f;

    for (int ks = 0; ks < KSTEPS; ++ks) {
        const int k0 = ks * BKp;

        // ---- stage A: entries e in {t, t+256} of 512 (= 8 mt x 64 lanes)
        #pragma unroll
        for (int half = 0; half < 2; ++half) {
            const int e  = t + 256 * half;
            const int mt = e >> 6;
            const int l  = e & 63;
            const int m  = (mt << 4) + (l & 15);
            const int kg = l >> 4;
            const int row = row0 + m;
            const int k   = k0 + kg * 8;
            const float* src = table + (size_t)row * EMB + k;
            float4 v0 = make_float4(0.f, 0.f, 0.f, 0.f);
            float4 v1 = make_float4(0.f, 0.f, 0.f, 0.f);
            if (row < VOCAB && k + 4 <= EMB) v0 = *(const float4*)(src);
            if (row < VOCAB && k + 8 <= EMB) v1 = *(const float4*)(src + 4);
            const float vv[8] = {v0.x, v0.y, v0.z, v0.w, v1.x, v1.y, v1.z, v1.w};
            f16x8 hi, lo;
            #pragma unroll
            for (int j = 0; j < 8; ++j) {
                const f16 h = (f16)vv[j];
                hi[j] = h;
                lo[j] = (f16)(vv[j] - (float)h);
            }
            *(f16x8*)&Af_hi[mt][l][0] = hi;
            *(f16x8*)&Af_lo[mt][l][0] = lo;
        }

        // ---- stage B: entries e in {t, t+256} (= 8 nt x 64 lanes); w1t is
        // pre-split fp16 and zero-padded, so these are plain 16B copies.
        #pragma unroll
        for (int half = 0; half < 2; ++half) {
            const int e  = t + 256 * half;
            const int nt = e >> 6;
            const int l  = e & 63;
            const int n  = (nt << 4) + (l & 15);
            const int kg = l >> 4;
            const size_t off = (size_t)n * KPAD + k0 + kg * 8;
            *(f16x8*)&Bf_hi[nt][l][0] = *(const f16x8*)(w1t_hi + off);
            *(f16x8*)&Bf_lo[nt][l][0] = *(const f16x8*)(w1t_lo + off);
        }
        __syncthreads();

        // ---- 48 mfma per wave: 2 m-tiles x 8 n-tiles x 3 passes
        f16x8 a_hi[2], a_lo[2];
        #pragma unroll
        for (int mt2 = 0; mt2 < 2; ++mt2) {
            a_hi[mt2] = *(const f16x8*)&Af_hi[2 * w + mt2][lane][0];
            a_lo[mt2] = *(const f16x8*)&Af_lo[2 * w + mt2][lane][0];
        }
        #pragma unroll
        for (int h = 0; h < 2; ++h) {
            f16x8 b_hi[4], b_lo[4];
            #pragma unroll
            for (int n4 = 0; n4 < 4; ++n4) {
                const int nt = h * 4 + n4;
                b_hi[n4] = *(const f16x8*)&Bf_hi[nt][lane][0];
                b_lo[n4] = *(const f16x8*)&Bf_lo[nt][lane][0];
            }
            #pragma unroll
            for (int mt2 = 0; mt2 < 2; ++mt2)
                #pragma unroll
                for (int n4 = 0; n4 < 4; ++n4) {
                    f32x4 c = acc[mt2][h * 4 + n4];
                    c = __builtin_amdgcn_mfma_f32_16x16x32_f16(a_hi[mt2], b_hi[n4], c, 0, 0, 0);
                    c = __builtin_amdgcn_mfma_f32_16x16x32_f16(a_hi[mt2], b_lo[n4], c, 0, 0, 0);
                    c = __builtin_amdgcn_mfma_f32_16x16x32_f16(a_lo[mt2], b_hi[n4], c, 0, 0, 0);
                    acc[mt2][h * 4 + n4] = c;
                }
        }
        __syncthreads();
    }

    // ---- epilogue: reg j of lane -> row 4*(lane>>4)+j, col lane&15.
    // 16-lane groups write 32B-contiguous segments per (nt,j).
    #pragma unroll
    for (int mt2 = 0; mt2 < 2; ++mt2) {
        const int rbase = row0 + (2 * w + mt2) * 16 + 4 * (lane >> 4);
        #pragma unroll
        for (int nt = 0; nt < 8; ++nt) {
            const int col = nt * 16 + (lane & 15);
            const f32x4 v = acc[mt2][nt];
            #pragma unroll
            for (int j = 0; j < 4; ++j) {
                const int row = rbase + j;
                if (row < VOCAB)
                    P[(size_t)row * HH + col] = (f16)v[j];
            }
        }
    }
}

// =====================================================================
// Kernel 2: gather-sum over fp16 P (256 B rows) + tiny MLP epilogue.
// UNCHANGED from v4 — this round's proj shrink forces it into top-5 so
// we finally see its real dur/FETCH/VALUBusy (H1 ~145us structural vs
// H2 fast + per-iteration harness overhead).
// =====================================================================
__global__ __launch_bounds__(256) void gather_mlp(
    const int*   __restrict__ x,        // [B, L]
    const int*   __restrict__ lengths,  // [B]
    const f16*   __restrict__ P,        // [VOCAB, HH] fp16
    const float* __restrict__ b1,       // [HH]
    const float* __restrict__ W2,       // [HH, OUT]
    const float* __restrict__ b2,       // [OUT]
    float*       __restrict__ out)      // [B, OUT]
{
    __shared__ int   idx_s[NSRT];
    __shared__ float part_s[16][HH];    // [t>>4][col] 8 KB
    __shared__ float h_s[HH];

    const int b    = blockIdx.x;
    const int t    = threadIdx.x;
    const int lane = t & 63;
    const int w    = t >> 6;

    idx_s[t] = (t < LL) ? x[b * LL + t] : 0x7FFFFFFF;
    __syncthreads();

    // ---- bitonic sort ascending over 256 slots
    #pragma unroll
    for (int k = 2; k <= NSRT; k <<= 1) {
        #pragma unroll
        for (int j = k >> 1; j > 0; j >>= 1) {
            const int ixj = t ^ j;
            if (ixj > t) {
                const int a0 = idx_s[t];
                const int a1 = idx_s[ixj];
                const bool up = ((t & k) == 0);
                if ((a0 > a1) == up) { idx_s[t] = a1; idx_s[ixj] = a0; }
            }
            __syncthreads();
        }
    }

    // wave w owns sorted positions [50w, 50w+50); lane j<50 holds row j
    const int myidx = (lane < RPW) ? idx_s[RPW * w + lane] : 0;

    const int c = lane & 15;            // 16B col chunk (halves 8c..8c+7)
    const size_t coff = (size_t)c * 8;

    float acc[8];
    #pragma unroll
    for (int j = 0; j < 8; ++j) acc[j] = 0.f;

    // ---- 12 iterations x 4 rows
    #pragma unroll
    for (int i = 0; i < 12; ++i) {
        const int r0 = __builtin_amdgcn_readlane(myidx, 4 * i + 0);
        const int r1 = __builtin_amdgcn_readlane(myidx, 4 * i + 1);
        const int r2 = __builtin_amdgcn_readlane(myidx, 4 * i + 2);
        const int r3 = __builtin_amdgcn_readlane(myidx, 4 * i + 3);
        const int rlo  = (lane & 16) ? r1 : r0;
        const int rhi  = (lane & 16) ? r3 : r2;
        const int ridx = (lane & 32) ? rhi : rlo;
        const f16x8 v = *(const f16x8*)(P + (size_t)ridx * HH + coff);
        #pragma unroll
        for (int j = 0; j < 8; ++j) acc[j] += (float)v[j];
    }
    // ---- tail: rows 48,49 on lane groups 0,1
    {
        const int r0 = __builtin_amdgcn_readlane(myidx, 48);
        const int r1 = __builtin_amdgcn_readlane(myidx, 49);
        const int ridx = (lane & 16) ? r1 : r0;
        const f16x8 v = *(const f16x8*)(P + (size_t)ridx * HH + coff);
        if (lane < 32) {
            #pragma unroll
            for (int j = 0; j < 8; ++j) acc[j] += (float)v[j];
        }
    }

    *(float4*)&part_s[t >> 4][c * 8]     = make_float4(acc[0], acc[1], acc[2], acc[3]);
    *(float4*)&part_s[t >> 4][c * 8 + 4] = make_float4(acc[4], acc[5], acc[6], acc[7]);
    __syncthreads();

    const float inv_len = 1.0f / (float)lengths[b];
    if (t < HH) {
        float s = 0.f;
        #pragma unroll
        for (int p = 0; p < 16; ++p) s += part_s[p][t];
        h_s[t] = fmaxf(fmaf(s, inv_len, b1[t]), 0.f);
    }
    __syncthreads();

    if (t < OUTD) {
        float o = b2[t];
        #pragma unroll
        for (int k = 0; k < HH; ++k)
            o = fmaf(h_s[k], W2[k * OUTD + t], o);
        out[b * OUTD + t] = o;
    }
}

// =====================================================================
// Fallback: prior session's proven fused kernel — used only if the
// workspace is too small.
// =====================================================================
__global__ __launch_bounds__(256) void fused_dnn(
    const int*   __restrict__ x,
    const int*   __restrict__ lengths,
    const float* __restrict__ table,
    const float* __restrict__ W1,
    const float* __restrict__ b1,
    const float* __restrict__ W2,
    const float* __restrict__ b2,
    float*       __restrict__ out)
{
    __shared__ int    idx_s[NSRT];
    __shared__ float4 part_s[4][76];
    __shared__ float  rep_s[EMB];
    __shared__ float  h_part[2][HH];
    __shared__ float  h_s[HH];

    const int b    = blockIdx.x;
    const int t    = threadIdx.x;
    const int w    = t >> 6;
    const int lane = t & 63;

    idx_s[t] = (t < LL) ? x[b * LL + t] : 0x7FFFFFFF;
    __syncthreads();

    #pragma unroll
    for (int k = 2; k <= NSRT; k <<= 1) {
        #pragma unroll
        for (int j = k >> 1; j > 0; j >>= 1) {
            const int ixj = t ^ j;
            if (ixj > t) {
                const int a0 = idx_s[t];
                const int a1 = idx_s[ixj];
                const bool up = ((t & k) == 0);
                if ((a0 > a1) == up) { idx_s[t] = a1; idx_s[ixj] = a0; }
            }
            __syncthreads();
        }
    }

    const int myidx = (lane < RPW) ? idx_s[w + 4 * lane] : 0;

    float4 acc_a = make_float4(0.f, 0.f, 0.f, 0.f);
    float4 acc_b = make_float4(0.f, 0.f, 0.f, 0.f);
    const bool hasb = (lane < (EMB / 4 - 64));

    #pragma unroll 5
    for (int i = 0; i < RPW; ++i) {
        const int ridx = __builtin_amdgcn_readlane(myidx, i);
        const float4* row = (const float4*)(table + (size_t)ridx * EMB);
        float4 va = row[lane];
        acc_a.x += va.x; acc_a.y += va.y; acc_a.z += va.z; acc_a.w += va.w;
        if (hasb) {
            float4 vb = row[64 + lane];
            acc_b.x += vb.x; acc_b.y += vb.y; acc_b.z += vb.z; acc_b.w += vb.w;
        }
    }

    part_s[w][lane] = acc_a;
    if (hasb) part_s[w][64 + lane] = acc_b;
    __syncthreads();

    const float inv_len = 1.0f / (float)lengths[b];
    const float* ps = (const float*)part_s;
    {
        float s = ps[t] + ps[304 + t] + ps[608 + t] + ps[912 + t];
        rep_s[t] = s * inv_len;
    }
    if (t < (EMB - 256)) {
        int c = 256 + t;
        float s = ps[c] + ps[304 + c] + ps[608 + c] + ps[912 + c];
        rep_s[c] = s * inv_len;
    }
    __syncthreads();

    {
        const int half = t >> 7;
        const int col  = t & 127;
        float hacc = (half == 0) ? b1[col] : 0.0f;
        const int k0 = half * (EMB / 2);
        #pragma unroll 5
        for (int k = k0; k < k0 + EMB / 2; ++k)
            hacc = fmaf(rep_s[k], W1[k * HH + col], hacc);
        h_part[half][col] = hacc;
    }
    __syncthreads();
    if (t < HH)
        h_s[t] = fmaxf(h_part[0][t] + h_part[1][t], 0.0f);
    __syncthreads();

    if (t < OUTD) {
        float oacc = b2[t];
        #pragma unroll
        for (int k = 0; k < HH; ++k)
            oacc = fmaf(h_s[k], W2[k * OUTD + t], oacc);
        out[b * OUTD + t] = oacc;
    }
}

extern "C" void kernel_launch(void* const* d_in, const int* in_sizes, int n_in,
                              void* d_out, int out_size, void* d_ws, size_t ws_size,
                              hipStream_t stream) {
    const int*   x       = (const int*)  d_in[0];
    const int*   lengths = (const int*)  d_in[1];
    const float* table   = (const float*)d_in[2];
    const float* W1      = (const float*)d_in[3];
    const float* b1      = (const float*)d_in[4];
    const float* W2      = (const float*)d_in[5];
    const float* b2      = (const float*)d_in[6];
    float*       out     = (float*)d_out;

    const size_t PELEMS  = (size_t)VOCAB * HH;          // 12.8M f16
    const size_t W1TELEMS = (size_t)HH * KPAD;          // 40960 f16
    const size_t NEED = (PELEMS + 2 * W1TELEMS) * sizeof(f16);   // ~25.8 MB

    if (d_ws != nullptr && ws_size >= NEED) {
        f16* P      = (f16*)d_ws;
        f16* w1t_hi = P + PELEMS;
        f16* w1t_lo = w1t_hi + W1TELEMS;
        w1t_prep<<<HH, KPAD, 0, stream>>>(W1, w1t_hi, w1t_lo);
        const int mtiles = (VOCAB + BMp - 1) / BMp;     // 782
        proj_mfma<<<mtiles, 256, 0, stream>>>(table, w1t_hi, w1t_lo, P);
        gather_mlp<<<BB, 256, 0, stream>>>(x, lengths, P, b1, W2, b2, out);
    } else {
        fused_dnn<<<BB, 256, 0, stream>>>(x, lengths, table, W1, b1, W2, b2, out);
    }
}